// Round 14
// baseline (165.488 us; speedup 1.0000x reference)
//
#include <hip/hip_runtime.h>
#include <hip/hip_bf16.h>

// Problem constants (fixed by setup_inputs)
#define BB 4
#define TT 2048
#define VV 512
#define CC 512
#define HH 4
#define DD 128
#define NB2 128          // 2*NB
#define NROWS (BB*TT)    // 8192
#define QC 64            // linear-attention chunk length
#define NCH (TT/QC)      // 32 chunks per sequence
#define SST 66           // padded LDS stride (ushorts)
#define EPS 1e-12f

typedef __attribute__((ext_vector_type(8))) short bf16x8;
typedef __attribute__((ext_vector_type(4))) float f32x4;
typedef unsigned short u16;

__device__ __forceinline__ void gl_lds16(const void* g, void* l) {
    __builtin_amdgcn_global_load_lds(
        (const __attribute__((address_space(1))) unsigned int*)g,
        (__attribute__((address_space(3))) unsigned int*)l, 16, 0, 0);
}
__device__ __forceinline__ u16 f2bu(float x) {
    __hip_bfloat16 h = __float2bfloat16(x);
    return *reinterpret_cast<u16*>(&h);
}
__device__ __forceinline__ float bu2f(u16 u) {
    __hip_bfloat16 h = *reinterpret_cast<__hip_bfloat16*>(&u);
    return __bfloat162float(h);
}
__device__ __forceinline__ uint4 pack8(float4 a, float4 b, float s) {
    u16 h[8] = {f2bu(a.x * s), f2bu(a.y * s), f2bu(a.z * s), f2bu(a.w * s),
                f2bu(b.x * s), f2bu(b.y * s), f2bu(b.z * s), f2bu(b.w * s)};
    return *(uint4*)h;
}

// ---------------------------------------------------------------------------
// prep_all4: qw/kw transpose+cast, zero norms, two small weight GEMMs.
// [validated r8-r13]
// ---------------------------------------------------------------------------
#define P4_TR  512
#define P4_Z   16
#define P4_WG  32
__global__ __launch_bounds__(256) void prep_all4(
    const float* __restrict__ qw, const float* __restrict__ kw,
    const float* __restrict__ basis, const float* __restrict__ v_coeffs,
    const float* __restrict__ o_coeffs, const float* __restrict__ out_scale,
    u16* __restrict__ wq, u16* __restrict__ wk,
    u16* __restrict__ v_wT, u16* __restrict__ o_ws, float* __restrict__ norms)
{
    __shared__ __align__(16) union {
        float tile[32][33];
        struct { u16 A[4096]; u16 B[4096]; } w;
    } sm;
    const int bi = blockIdx.x, t = threadIdx.x;
    if (bi < P4_TR) {
        int id = bi;
        const int z = id >> 8; id &= 255;
        const float* in = z ? kw : qw;
        u16* outT = z ? wk : wq;
        const int bx = (id & 15) * 32, by = (id >> 4) * 32;
        const int tx = t & 31, ty = t >> 5;
        #pragma unroll
        for (int r = 0; r < 32; r += 8)
            sm.tile[ty + r][tx] = in[(size_t)(by + ty + r) * CC + bx + tx];
        __syncthreads();
        #pragma unroll
        for (int r = 0; r < 32; r += 8)
            outT[(size_t)(bx + ty + r) * VV + by + tx] = f2bu(sm.tile[tx][ty + r]);
    } else if (bi < P4_TR + P4_Z) {
        int idx = (bi - P4_TR) * 256 + t;
        ((float4*)norms)[idx] = make_float4(0.f, 0.f, 0.f, 0.f);
    } else {
        int id = bi - (P4_TR + P4_Z);
        const int sec = id >> 4, rem = id & 15;
        const int m0 = (rem >> 2) * 128, n0 = (rem & 3) * 128;
        const float* Af = sec ? basis : v_coeffs;
        const float* Bf = sec ? o_coeffs : basis;
        u16* Cp = sec ? o_ws : v_wT;
        const float scB = sec ? out_scale[0] : 1.f;
        const int wave = t >> 6, lane = t & 63;
        const int qq = lane >> 4, l16 = lane & 15;
        const int wm = (wave >> 1) * 64, wn = (wave & 1) * 64;
        const int s0 = wave * 128 + lane, s1 = s0 + 64;
        const int r0 = s0 >> 2, c0 = ((s0 & 3) - (r0 >> 1)) & 3;
        const int r1 = s1 >> 2, c1 = ((s1 & 3) - (r1 >> 1)) & 3;
        f32x4 acc[4][4];
        #pragma unroll
        for (int i = 0; i < 4; ++i)
            #pragma unroll
            for (int j = 0; j < 4; ++j) acc[i][j] = (f32x4){0.f, 0.f, 0.f, 0.f};
        for (int k0 = 0; k0 < NB2; k0 += 32) {
            __syncthreads();
            {
                const float* p0 = Af + (size_t)(m0 + r0) * NB2 + k0 + c0 * 8;
                const float* p1 = Af + (size_t)(m0 + r1) * NB2 + k0 + c1 * 8;
                *(uint4*)&sm.w.A[s0 * 8] = pack8(((const float4*)p0)[0], ((const float4*)p0)[1], 1.f);
                *(uint4*)&sm.w.A[s1 * 8] = pack8(((const float4*)p1)[0], ((const float4*)p1)[1], 1.f);
                const float* q0 = Bf + (size_t)(n0 + r0) * NB2 + k0 + c0 * 8;
                const float* q1 = Bf + (size_t)(n0 + r1) * NB2 + k0 + c1 * 8;
                *(uint4*)&sm.w.B[s0 * 8] = pack8(((const float4*)q0)[0], ((const float4*)q0)[1], scB);
                *(uint4*)&sm.w.B[s1 * 8] = pack8(((const float4*)q1)[0], ((const float4*)q1)[1], scB);
            }
            __syncthreads();
            bf16x8 af[4], bfr[4];
            #pragma unroll
            for (int mt = 0; mt < 4; ++mt) {
                const int r = wm + mt * 16 + l16;
                af[mt] = *(const bf16x8*)&sm.w.A[(r * 4 + ((qq + (r >> 1)) & 3)) * 8];
            }
            #pragma unroll
            for (int nt = 0; nt < 4; ++nt) {
                const int r = wn + nt * 16 + l16;
                bfr[nt] = *(const bf16x8*)&sm.w.B[(r * 4 + ((qq + (r >> 1)) & 3)) * 8];
            }
            #pragma unroll
            for (int mt = 0; mt < 4; ++mt)
                #pragma unroll
                for (int nt = 0; nt < 4; ++nt)
                    acc[mt][nt] = __builtin_amdgcn_mfma_f32_16x16x32_bf16(
                        af[mt], bfr[nt], acc[mt][nt], 0, 0, 0);
        }
        #pragma unroll
        for (int mt = 0; mt < 4; ++mt)
            #pragma unroll
            for (int rr = 0; rr < 4; ++rr) {
                int grow = m0 + wm + mt * 16 + qq * 4 + rr;
                #pragma unroll
                for (int nt = 0; nt < 4; ++nt)
                    Cp[(size_t)grow * 512 + n0 + wn + nt * 16 + l16] = f2bu(acc[mt][nt][rr]);
            }
    }
}

// ---------------------------------------------------------------------------
// q/k/v projection, 384 blocks of 256x128 tiles (BK=32 dbuf): per-barrier
// MFMA doubles (32/wave) and block count halves vs r10 -> 2x fewer
// barrier-drain events. LDS 48KB; VGPR ~240 -> 2 blocks/CU.
// Each wave owns 64 rows x full 128 cols (acc[4][8]).
// fp32-A reg staging w/ prefetch distance 2 [r9]; XCD cluster (384%8==0).
// ---------------------------------------------------------------------------
__global__ __launch_bounds__(256) void gemm_qkv3(
    const float* __restrict__ x, const u16* __restrict__ wcat,
    u16* __restrict__ qo, u16* __restrict__ ko, u16* __restrict__ vo,
    float* __restrict__ norms)
{
    __shared__ __align__(16) u16 As[2 * 8192];   // 2 x 16KB (256 rows x 32)
    __shared__ __align__(16) u16 Bs[2 * 4096];   // 2 x 8KB  (128 rows x 32)
    const int t = threadIdx.x;
    const int wave = t >> 6, lane = t & 63;
    const int qq = lane >> 4, l16 = lane & 15;
    const int bid = blockIdx.x;
    const int fid = (bid & 7) * 48 + (bid >> 3);   // XCD-cluster
    const int mx = fid % 12;
    const int sec = mx >> 2;
    const int n0 = (mx & 3) * 128;
    const int m0 = (fid / 12) * 256;
    const int wm = wave * 64;                      // wave owns rows wm..wm+63
    const int K = VV;
    const u16* Bt = wcat + (size_t)sec * VV * CC;

    // A: 1024 slots of 16B; 4 per thread. slot s: row r=s>>2, chunk ((s&3)-(r>>1))&3
    const float* gax[4];
    int sA[4];
    #pragma unroll
    for (int i = 0; i < 4; ++i) {
        sA[i] = t + 256 * i;
        const int r = sA[i] >> 2, c = ((sA[i] & 3) - (r >> 1)) & 3;
        gax[i] = x + (size_t)(m0 + r) * K + c * 8;
    }
    // B: 512 slots; gl_lds wave-base + per-lane source (identical to r10)
    const int s0 = wave * 128 + lane, s1 = s0 + 64;
    const int rB0 = s0 >> 2, cB0 = ((s0 & 3) - (rB0 >> 1)) & 3;
    const int rB1 = s1 >> 2, cB1 = ((s1 & 3) - (rB1 >> 1)) & 3;
    const u16* gb0 = Bt + (size_t)(n0 + rB0) * K + cB0 * 8;
    const u16* gb1 = Bt + (size_t)(n0 + rB1) * K + cB1 * 8;
    const int lo0 = (wave * 128) * 8, lo1 = lo0 + 512;

    // prologue
    #pragma unroll
    for (int i = 0; i < 4; ++i) {
        float4 f0 = ((const float4*)gax[i])[0];
        float4 f1 = ((const float4*)gax[i])[1];
        *(uint4*)&As[sA[i] * 8] = pack8(f0, f1, 1.f);
    }
    gl_lds16(gb0, Bs + lo0);
    gl_lds16(gb1, Bs + lo1);
    float4 na0[4], na1[4];
    #pragma unroll
    for (int i = 0; i < 4; ++i) {
        na0[i] = ((const float4*)(gax[i] + 32))[0];
        na1[i] = ((const float4*)(gax[i] + 32))[1];
    }

    f32x4 acc[4][8];
    #pragma unroll
    for (int i = 0; i < 4; ++i)
        #pragma unroll
        for (int j = 0; j < 8; ++j) acc[i][j] = (f32x4){0.f, 0.f, 0.f, 0.f};

    int ib = 0;
    for (int k0 = 0; k0 < K; k0 += 32, ib ^= 1) {
        __syncthreads();                 // buf ib ready
        if (k0 + 32 < K) {
            #pragma unroll
            for (int i = 0; i < 4; ++i)
                *(uint4*)&As[(ib ^ 1) * 8192 + sA[i] * 8] = pack8(na0[i], na1[i], 1.f);
            gl_lds16(gb0 + k0 + 32, Bs + (ib ^ 1) * 4096 + lo0);
            gl_lds16(gb1 + k0 + 32, Bs + (ib ^ 1) * 4096 + lo1);
        }
        if (k0 + 64 < K) {
            #pragma unroll
            for (int i = 0; i < 4; ++i) {
                na0[i] = ((const float4*)(gax[i] + k0 + 64))[0];
                na1[i] = ((const float4*)(gax[i] + k0 + 64))[1];
            }
        }
        const u16* Ac = As + ib * 8192;
        const u16* Bc = Bs + ib * 4096;
        bf16x8 af[4], bfr[8];
        #pragma unroll
        for (int mt = 0; mt < 4; ++mt) {
            const int r = wm + mt * 16 + l16;
            af[mt] = *(const bf16x8*)&Ac[(r * 4 + ((qq + (r >> 1)) & 3)) * 8];
        }
        #pragma unroll
        for (int nt = 0; nt < 8; ++nt) {
            const int r = nt * 16 + l16;
            bfr[nt] = *(const bf16x8*)&Bc[(r * 4 + ((qq + (r >> 1)) & 3)) * 8];
        }
        #pragma unroll
        for (int mt = 0; mt < 4; ++mt)
            #pragma unroll
            for (int nt = 0; nt < 8; ++nt)
                acc[mt][nt] = __builtin_amdgcn_mfma_f32_16x16x32_bf16(
                    af[mt], bfr[nt], acc[mt][nt], 0, 0, 0);
    }

    u16* outp = sec == 0 ? qo : (sec == 1 ? ko : vo);
    #pragma unroll
    for (int mt = 0; mt < 4; ++mt)
        #pragma unroll
        for (int r = 0; r < 4; ++r) {
            int grow = m0 + wm + mt * 16 + qq * 4 + r;
            #pragma unroll
            for (int nt = 0; nt < 8; ++nt)
                outp[(size_t)grow * CC + n0 + nt * 16 + l16] =
                    f2bu(acc[mt][nt][r]);
        }
    if (sec < 2) {
        float* np = sec == 0 ? norms : norms + NROWS;
        #pragma unroll
        for (int mt = 0; mt < 4; ++mt)
            #pragma unroll
            for (int r = 0; r < 4; ++r) {
                float s = 0.f;
                #pragma unroll
                for (int nt = 0; nt < 8; ++nt) {
                    float v = acc[mt][nt][r];
                    s = fmaf(v, v, s);
                }
                s += __shfl_xor(s, 1, 64);
                s += __shfl_xor(s, 2, 64);
                s += __shfl_xor(s, 4, 64);
                s += __shfl_xor(s, 8, 64);
                if (l16 == 0)
                    atomicAdd(&np[m0 + wm + mt * 16 + qq * 4 + r], s);
            }
    }
}

// ---------------------------------------------------------------------------
// per-chunk local states via MFMA, bh-major XCD swizzle [r13]
// ---------------------------------------------------------------------------
__global__ __launch_bounds__(256) void state_local(
    const u16* __restrict__ kb, const u16* __restrict__ vb,
    const float* __restrict__ norms_k, const float* __restrict__ dlog,
    u16* __restrict__ statesb)
{
    __shared__ __align__(16) u16 vT[DD][SST];
    __shared__ __align__(16) u16 kT[DD][SST];
    const int bid = blockIdx.x;
    const int fidx = (bid & 7) * 64 + (bid >> 3);
    const int bh = fidx >> 5, c = fidx & 31;
    const int b = bh >> 2, h = bh & 3;
    const float lam = 1.f / (1.f + __expf(-dlog[h]));
    const float l2lam = log2f(lam);
    const int t = threadIdx.x;
    const int row0 = b * TT + c * QC;
    const size_t gbase = (size_t)row0 * CC + h * DD;

    {
        const int j2 = t & 31, d0 = (t >> 5) * 16;
        const int jj0 = 2 * j2, jj1 = jj0 + 1;
        const float w0 = exp2f((float)jj0 * l2lam);
        const float w1 = exp2f((float)jj1 * l2lam);
        const float rk0 = 1.f / fmaxf(sqrtf(norms_k[row0 + jj0]), EPS);
        const float rk1 = 1.f / fmaxf(sqrtf(norms_k[row0 + jj1]), EPS);
        u16 k0a[16], k1a[16], v0a[16], v1a[16];
        const u16* k0p = kb + gbase + (size_t)jj0 * CC + d0;
        const u16* k1p = kb + gbase + (size_t)jj1 * CC + d0;
        const u16* v0p = vb + gbase + (size_t)jj0 * CC + d0;
        const u16* v1p = vb + gbase + (size_t)jj1 * CC + d0;
        *(uint4*)&k0a[0] = *(const uint4*)k0p; *(uint4*)&k0a[8] = *(const uint4*)(k0p + 8);
        *(uint4*)&k1a[0] = *(const uint4*)k1p; *(uint4*)&k1a[8] = *(const uint4*)(k1p + 8);
        *(uint4*)&v0a[0] = *(const uint4*)v0p; *(uint4*)&v0a[8] = *(const uint4*)(v0p + 8);
        *(uint4*)&v1a[0] = *(const uint4*)v1p; *(uint4*)&v1a[8] = *(const uint4*)(v1p + 8);
        #pragma unroll
        for (int i = 0; i < 16; ++i) {
            unsigned int kw = (unsigned int)f2bu(bu2f(k0a[i]) * rk0)
                            | ((unsigned int)f2bu(bu2f(k1a[i]) * rk1) << 16);
            *(unsigned int*)&kT[d0 + i][jj0] = kw;
            unsigned int vw = (unsigned int)f2bu(bu2f(v0a[i]) * w0)
                            | ((unsigned int)f2bu(bu2f(v1a[i]) * w1) << 16);
            *(unsigned int*)&vT[d0 + i][jj0] = vw;
        }
    }
    __syncthreads();

    const int wave = t >> 6, lane = t & 63;
    const int quad = lane >> 4, l16 = lane & 15;
    f32x4 acc[2][8];
    #pragma unroll
    for (int i = 0; i < 2; ++i)
        #pragma unroll
        for (int j = 0; j < 8; ++j) acc[i][j] = (f32x4){0.f, 0.f, 0.f, 0.f};

    #pragma unroll
    for (int s = 0; s < 2; ++s) {
        bf16x8 af[2];
        #pragma unroll
        for (int mt = 0; mt < 2; ++mt)
            af[mt] = *(const bf16x8*)&vT[wave * 32 + mt * 16 + l16][s * 32 + quad * 8];
        #pragma unroll
        for (int nt = 0; nt < 8; ++nt) {
            bf16x8 bk = *(const bf16x8*)&kT[nt * 16 + l16][s * 32 + quad * 8];
            #pragma unroll
            for (int mt = 0; mt < 2; ++mt)
                acc[mt][nt] = __builtin_amdgcn_mfma_f32_16x16x32_bf16(
                    af[mt], bk, acc[mt][nt], 0, 0, 0);
        }
    }
    u16* so = statesb + ((size_t)(bh * NCH + c) << 14);
    #pragma unroll
    for (int mt = 0; mt < 2; ++mt)
        #pragma unroll
        for (int rr = 0; rr < 4; ++rr) {
            const int d = wave * 32 + mt * 16 + quad * 4 + rr;
            #pragma unroll
            for (int nt = 0; nt < 8; ++nt)
                so[(size_t)d * DD + nt * 16 + l16] = f2bu(acc[mt][nt][rr]);
        }
}

// ---------------------------------------------------------------------------
// suffix combine: register scan, bh-major swizzle [r13]
// ---------------------------------------------------------------------------
__global__ __launch_bounds__(256) void state_combine512(
    const float* __restrict__ dlog, u16* __restrict__ statesb)
{
    const int bid = blockIdx.x;
    const int fidx = (bid & 7) * 64 + (bid >> 3);
    const int bh = fidx >> 5, part = fidx & 31;
    const int h = bh & 3;
    const float lam = 1.f / (1.f + __expf(-dlog[h]));
    const float lamQ = exp2f((float)QC * log2f(lam));
    const int t = threadIdx.x;
    unsigned int* pb = (unsigned int*)(statesb + ((size_t)(bh * NCH) << 14))
                       + part * 256 + t;
    unsigned int vals[NCH];
    #pragma unroll
    for (int c = 0; c < NCH; ++c) vals[c] = pb[(size_t)c * 8192];
    float run0 = 0.f, run1 = 0.f;
    #pragma unroll
    for (int c = NCH - 1; c >= 0; --c) {
        float t0 = bu2f((u16)(vals[c] & 0xffffu));
        float t1 = bu2f((u16)(vals[c] >> 16));
        pb[(size_t)c * 8192] = (unsigned int)f2bu(run0)
                             | ((unsigned int)f2bu(run1) << 16);
        run0 = fmaf(lamQ, run0, t0);
        run1 = fmaf(lamQ, run1, t1);
    }
}

// ---------------------------------------------------------------------------
// fused MFMA attention, bh-major swizzle [r13]
// ---------------------------------------------------------------------------
__global__ __launch_bounds__(256) void attention_fused(
    const u16* __restrict__ qb, const u16* __restrict__ kb,
    const u16* __restrict__ vb, const u16* __restrict__ statesb,
    const float* __restrict__ norms, const float* __restrict__ dlog,
    u16* __restrict__ retb)
{
    __shared__ __align__(16) u16 qks[2 * QC * DD];
    __shared__ __align__(16) u16 vsT[DD][SST];
    __shared__ __align__(16) u16 ss[QC][SST];
    __shared__ float rql[QC], rkl[QC];

    const int bid = blockIdx.x;
    const int fidx = (bid & 7) * 64 + (bid >> 3);
    const int bh = fidx >> 5, c = fidx & 31;
    const int b = bh >> 2, h = bh & 3;
    const float lam = 1.f / (1.f + __expf(-dlog[h]));
    const float l2lam = log2f(lam);
    const int t = threadIdx.x;
    const int row0 = b * TT + c * QC;
    const size_t base = (size_t)row0 * CC + h * DD;

    const int wave = t >> 6, lane = t & 63;
    const int quad = lane >> 4, l16 = lane & 15;
    const int r0 = wave * 16;

    {
        const int lrow = lane >> 4, cch = lane & 15;
        #pragma unroll
        for (int u = 0; u < 4; ++u) {
            const int R = wave * 16 + u * 4;
            const int gr = R + lrow;
            const int cq = (cch - gr) & 15;
            gl_lds16(qb + base + (size_t)gr * CC + cq * 8, &qks[R * DD]);
            gl_lds16(kb + base + (size_t)gr * CC + cq * 8, &qks[(QC + R) * DD]);
        }
    }
    if (t < QC)            rql[t]      = 1.f / fmaxf(sqrtf(norms[row0 + t]), EPS);
    else if (t < 2 * QC)   rkl[t - QC] = 1.f / fmaxf(sqrtf(norms[NROWS + row0 + t - QC]), EPS);
    {
        const int j2 = t & 31, d0 = (t >> 5) * 16;
        const u16* v0 = vb + base + (size_t)(2 * j2) * CC + d0;
        const u16* v1 = v0 + CC;
        uint4 a0 = *(const uint4*)v0;
        uint4 a1 = *(const uint4*)(v0 + 8);
        uint4 b0 = *(const uint4*)v1;
        uint4 b1 = *(const uint4*)(v1 + 8);
        const u16* ap0 = (const u16*)&a0; const u16* ap1 = (const u16*)&a1;
        const u16* bp0 = (const u16*)&b0; const u16* bp1 = (const u16*)&b1;
        #pragma unroll
        for (int i = 0; i < 8; ++i) {
            *(unsigned int*)&vsT[d0 + i][2 * j2] =
                (unsigned int)ap0[i] | ((unsigned int)bp0[i] << 16);
            *(unsigned int*)&vsT[d0 + 8 + i][2 * j2] =
                (unsigned int)ap1[i] | ((unsigned int)bp1[i] << 16);
        }
    }
    __syncthreads();

    bf16x8 aq[4];
    #pragma unroll
    for (int kq = 0; kq < 4; ++kq) {
        const int r = r0 + l16;
        aq[kq] = *(const bf16x8*)&qks[r * DD + ((kq * 4 + quad + r) & 15) * 8];
    }

    f32x4 accs[4];
    #pragma unroll
    for (int nt = 0; nt < 4; ++nt) accs[nt] = (f32x4){0.f, 0.f, 0.f, 0.f};
    #pragma unroll
    for (int nt = 0; nt < 4; ++nt)
        #pragma unroll
        for (int kq = 0; kq < 4; ++kq) {
            const int rk_ = nt * 16 + l16;
            bf16x8 bk = *(const bf16x8*)&qks[(QC + rk_) * DD + ((kq * 4 + quad + rk_) & 15) * 8];
            accs[nt] = __builtin_amdgcn_mfma_f32_16x16x32_bf16(aq[kq], bk, accs[nt], 0, 0, 0);
        }

    #pragma unroll
    for (int nt = 0; nt < 4; ++nt) {
        const int j = nt * 16 + l16;
        const float rkj = rkl[j];
        #pragma unroll
        for (int rr = 0; rr < 4; ++rr) {
            const int i = r0 + quad * 4 + rr;
            const int di = j - i;
            float p = (di > 0) ? accs[nt][rr] * exp2f((float)(di - 1) * l2lam) * rkj : 0.f;
            ss[i][j] = f2bu(p);
        }
    }
    __syncthreads();

    const u16* sb = statesb + ((size_t)(bh * NCH + c) << 14);
    {
        const int drow = lane >> 4, cch = lane & 15;
        #pragma unroll
        for (int u = 0; u < 8; ++u) {
            const int D = wave * 32 + u * 4;
            const int gd = D + drow;
            const int cq = (cch - gd) & 15;
            gl_lds16(sb + (size_t)gd * DD + cq * 8, &qks[D * DD]);
        }
    }
    bf16x8 ap[2];
    #pragma unroll
    for (int kj = 0; kj < 2; ++kj)
        ap[kj] = *(const bf16x8*)&ss[r0 + l16][kj * 32 + quad * 8];
    f32x4 accd[8];
    #pragma unroll
    for (int nt = 0; nt < 8; ++nt) accd[nt] = (f32x4){0.f, 0.f, 0.f, 0.f};
    #pragma unroll
    for (int nt = 0; nt < 8; ++nt)
        #pragma unroll
        for (int kj = 0; kj < 2; ++kj) {
            bf16x8 bv = *(const bf16x8*)&vsT[nt * 16 + l16][kj * 32 + quad * 8];
            accd[nt] = __builtin_amdgcn_mfma_f32_16x16x32_bf16(ap[kj], bv, accd[nt], 0, 0, 0);
        }
    __syncthreads();

    f32x4 accc[8];
    #pragma unroll
    for (int nt = 0; nt < 8; ++nt) accc[nt] = (f32x4){0.f, 0.f, 0.f, 0.f};
    #pragma unroll
    for (int nt = 0; nt < 8; ++nt)
        #pragma unroll
        for (int kq = 0; kq < 4; ++kq) {
            const int d = nt * 16 + l16;
            bf16x8 bs_ = *(const bf16x8*)&qks[d * DD + ((kq * 4 + quad + d) & 15) * 8];
            accc[nt] = __builtin_amdgcn_mfma_f32_16x16x32_bf16(aq[kq], bs_, accc[nt], 0, 0, 0);
        }

    u16* rb = retb + (size_t)row0 * CC + h * DD;
    #pragma unroll
    for (int rr = 0; rr < 4; ++rr) {
        const int ii = r0 + quad * 4 + rr;
        const float wrow = exp2f((float)(QC - 1 - ii) * l2lam);
        const float rq = rql[ii];
        #pragma unroll
        for (int nt = 0; nt < 8; ++nt) {
            float val = (accd[nt][rr] + wrow * accc[nt][rr]) * rq;
            rb[(size_t)ii * CC + nt * 16 + l16] = f2bu(val);
        }
    }
}

// ---------------------------------------------------------------------------
// output projection, 64x128 tile, XCD-clustered [validated r10]
// ---------------------------------------------------------------------------
__global__ __launch_bounds__(256) void gemm_out64(
    const u16* __restrict__ A, const u16* __restrict__ Bt, float* __restrict__ C)
{
    __shared__ __align__(16) u16 As[4096];
    __shared__ __align__(16) u16 Bs[8192];
    const int t = threadIdx.x;
    const int wave = t >> 6, lane = t & 63;
    const int qq = lane >> 4, l16 = lane & 15;
    const int bid = blockIdx.x;
    const int fid = (bid & 7) * 64 + (bid >> 3);
    const int m0 = (fid >> 2) * 64, n0 = (fid & 3) * 128;
    const int wm = (wave >> 1) * 32, wn = (wave & 1) * 64;
    const int N = VV, K = CC;

    const int sA = wave * 64 + lane;
    const int rA = sA >> 2, cA = ((sA & 3) - (rA >> 1)) & 3;
    const int sB0 = wave * 128 + lane, sB1 = sB0 + 64;
    const int rB0 = sB0 >> 2, cB0 = ((sB0 & 3) - (rB0 >> 1)) & 3;
    const int rB1 = sB1 >> 2, cB1 = ((sB1 & 3) - (rB1 >> 1)) & 3;
    const u16* ga  = A  + (size_t)(m0 + rA) * K + cA * 8;
    const u16* gb0 = Bt + (size_t)(n0 + rB0) * K + cB0 * 8;
    const u16* gb1 = Bt + (size_t)(n0 + rB1) * K + cB1 * 8;
    const int loA = wave * 512, loB0 = wave * 1024, loB1 = wave * 1024 + 512;

    gl_lds16(ga, As + loA);
    gl_lds16(gb0, Bs + loB0);
    gl_lds16(gb1, Bs + loB1);

    f32x4 acc[2][4];
    #pragma unroll
    for (int i = 0; i < 2; ++i)
        #pragma unroll
        for (int j = 0; j < 4; ++j) acc[i][j] = (f32x4){0.f, 0.f, 0.f, 0.f};

    int ib = 0;
    for (int k0 = 0; k0 < K; k0 += 32, ib ^= 1) {
        __syncthreads();
        if (k0 + 32 < K) {
            gl_lds16(ga + k0 + 32,  As + (ib ^ 1) * 2048 + loA);
            gl_lds16(gb0 + k0 + 32, Bs + (ib ^ 1) * 4096 + loB0);
            gl_lds16(gb1 + k0 + 32, Bs + (ib ^ 1) * 4096 + loB1);
        }
        const u16* Ac = As + ib * 2048;
        const u16* Bc = Bs + ib * 4096;
        bf16x8 af[2], bfr[4];
        #pragma unroll
        for (int mt = 0; mt < 2; ++mt) {
            const int r = wm + mt * 16 + l16;
            af[mt] = *(const bf16x8*)&Ac[(r * 4 + ((qq + (r >> 1)) & 3)) * 8];
        }
        #pragma unroll
        for (int nt = 0; nt < 4; ++nt) {
            const int r = wn + nt * 16 + l16;
            bfr[nt] = *(const bf16x8*)&Bc[(r * 4 + ((qq + (r >> 1)) & 3)) * 8];
        }
        #pragma unroll
        for (int mt = 0; mt < 2; ++mt)
            #pragma unroll
            for (int nt = 0; nt < 4; ++nt)
                acc[mt][nt] = __builtin_amdgcn_mfma_f32_16x16x32_bf16(
                    af[mt], bfr[nt], acc[mt][nt], 0, 0, 0);
    }
    #pragma unroll
    for (int mt = 0; mt < 2; ++mt)
        #pragma unroll
        for (int r = 0; r < 4; ++r) {
            int grow = m0 + wm + mt * 16 + qq * 4 + r;
            #pragma unroll
            for (int nt = 0; nt < 4; ++nt)
                C[(size_t)grow * N + n0 + wn + nt * 16 + l16] = acc[mt][nt][r];
        }
}

// ---------------------------------------------------------------------------
extern "C" void kernel_launch(void* const* d_in, const int* in_sizes, int n_in,
                              void* d_out, int out_size, void* d_ws, size_t ws_size,
                              hipStream_t stream) {
    const float* x         = (const float*)d_in[0];
    const float* basis     = (const float*)d_in[1];
    const float* qw        = (const float*)d_in[2];
    const float* kw        = (const float*)d_in[3];
    const float* v_coeffs  = (const float*)d_in[4];
    const float* o_coeffs  = (const float*)d_in[5];
    const float* dlog      = (const float*)d_in[6];
    const float* out_scale = (const float*)d_in[7];
    float* out             = (float*)d_out;

    u16* p = (u16*)d_ws;
    u16* qb      = p;                                   // 8192*512 bf16
    u16* kb      = qb + (size_t)NROWS * CC;
    u16* vb      = kb + (size_t)NROWS * CC;
    u16* statesb = vb + (size_t)NROWS * CC;             // 16*32*16384 bf16
    u16* retb    = statesb + (size_t)BB * HH * NCH * DD * DD;
    u16* wcat    = retb + (size_t)NROWS * CC;           // 3 x 512x512 bf16
    u16* o_ws    = wcat + 3 * (size_t)VV * CC;
    float* norms = (float*)(o_ws + (size_t)VV * CC);    // 2 x 8192 fp32 (q, k)

    // 1. transposes / zero norms / small weight GEMMs
    prep_all4<<<P4_TR + P4_Z + P4_WG, 256, 0, stream>>>(
        qw, kw, basis, v_coeffs, o_coeffs, out_scale,
        wcat, wcat + (size_t)VV * CC, wcat + 2 * (size_t)VV * CC, o_ws, norms);
    // 2. q/k/v projection (256x128 tiles, BK=32, XCD-clustered)
    gemm_qkv3<<<384, 256, 0, stream>>>(x, wcat, qb, kb, vb, norms);
    // 3. chunked linear attention (bh-major XCD pinning)
    state_local     <<<512, 256, 0, stream>>>(kb, vb, norms + NROWS, dlog, statesb);
    state_combine512<<<512, 256, 0, stream>>>(dlog, statesb);
    attention_fused <<<512, 256, 0, stream>>>(qb, kb, vb, statesb, norms, dlog, retb);
    // 4. output projection (o_ws includes out_scale), fp32 out (XCD-clustered)
    gemm_out64<<<512, 256, 0, stream>>>(retb, o_ws, out);
}

// Round 15
// 147.404 us; speedup vs baseline: 1.1227x; 1.1227x over previous
//
#include <hip/hip_runtime.h>
#include <hip/hip_bf16.h>

// Problem constants (fixed by setup_inputs)
#define BB 4
#define TT 2048
#define VV 512
#define CC 512
#define HH 4
#define DD 128
#define NB2 128          // 2*NB
#define NROWS (BB*TT)    // 8192
#define QC 64            // linear-attention chunk length
#define NCH (TT/QC)      // 32 chunks per sequence
#define SST 66           // padded LDS stride (ushorts)
#define EPS 1e-12f

typedef __attribute__((ext_vector_type(8))) short bf16x8;
typedef __attribute__((ext_vector_type(4))) float f32x4;
typedef unsigned short u16;

__device__ __forceinline__ void gl_lds16(const void* g, void* l) {
    __builtin_amdgcn_global_load_lds(
        (const __attribute__((address_space(1))) unsigned int*)g,
        (__attribute__((address_space(3))) unsigned int*)l, 16, 0, 0);
}
__device__ __forceinline__ u16 f2bu(float x) {
    __hip_bfloat16 h = __float2bfloat16(x);
    return *reinterpret_cast<u16*>(&h);
}
__device__ __forceinline__ float bu2f(u16 u) {
    __hip_bfloat16 h = *reinterpret_cast<__hip_bfloat16*>(&u);
    return __bfloat162float(h);
}
__device__ __forceinline__ uint4 pack8(float4 a, float4 b, float s) {
    u16 h[8] = {f2bu(a.x * s), f2bu(a.y * s), f2bu(a.z * s), f2bu(a.w * s),
                f2bu(b.x * s), f2bu(b.y * s), f2bu(b.z * s), f2bu(b.w * s)};
    return *(uint4*)h;
}

// ---------------------------------------------------------------------------
// prep_all4: (a) qw/kw transpose+cast, (b) zero norms, (c) two small weight
// GEMMs (v_wT = v_coeffs@basis^T, o_ws = basis@(o_coeffs*sc)^T), fp32
// reg-staged. [validated r8-r10]
// ---------------------------------------------------------------------------
#define P4_TR  512                   // 256 32x32 tiles x 2 inputs
#define P4_Z   16                    // 16384 floats / (256*4)
#define P4_WG  32                    // 2 GEMMs x (4 m-tiles x 4 n-tiles)
__global__ __launch_bounds__(256) void prep_all4(
    const float* __restrict__ qw, const float* __restrict__ kw,
    const float* __restrict__ basis, const float* __restrict__ v_coeffs,
    const float* __restrict__ o_coeffs, const float* __restrict__ out_scale,
    u16* __restrict__ wq, u16* __restrict__ wk,
    u16* __restrict__ v_wT, u16* __restrict__ o_ws, float* __restrict__ norms)
{
    __shared__ __align__(16) union {
        float tile[32][33];
        struct { u16 A[4096]; u16 B[4096]; } w;   // BK=32 staging
    } sm;
    const int bi = blockIdx.x, t = threadIdx.x;
    if (bi < P4_TR) {
        int id = bi;
        const int z = id >> 8; id &= 255;
        const float* in = z ? kw : qw;
        u16* outT = z ? wk : wq;
        const int bx = (id & 15) * 32, by = (id >> 4) * 32;
        const int tx = t & 31, ty = t >> 5;
        #pragma unroll
        for (int r = 0; r < 32; r += 8)
            sm.tile[ty + r][tx] = in[(size_t)(by + ty + r) * CC + bx + tx];
        __syncthreads();
        #pragma unroll
        for (int r = 0; r < 32; r += 8)
            outT[(size_t)(bx + ty + r) * VV + by + tx] = f2bu(sm.tile[tx][ty + r]);
    } else if (bi < P4_TR + P4_Z) {
        int idx = (bi - P4_TR) * 256 + t;
        ((float4*)norms)[idx] = make_float4(0.f, 0.f, 0.f, 0.f);
    } else {
        // small weight GEMMs, M=N=512, K=128, 128x128 tile, fp32 reg-staged.
        int id = bi - (P4_TR + P4_Z);
        const int sec = id >> 4, rem = id & 15;
        const int m0 = (rem >> 2) * 128, n0 = (rem & 3) * 128;
        const float* Af = sec ? basis : v_coeffs;
        const float* Bf = sec ? o_coeffs : basis;
        u16* Cp = sec ? o_ws : v_wT;
        const float scB = sec ? out_scale[0] : 1.f;
        const int wave = t >> 6, lane = t & 63;
        const int qq = lane >> 4, l16 = lane & 15;
        const int wm = (wave >> 1) * 64, wn = (wave & 1) * 64;
        const int s0 = wave * 128 + lane, s1 = s0 + 64;
        const int r0 = s0 >> 2, c0 = ((s0 & 3) - (r0 >> 1)) & 3;
        const int r1 = s1 >> 2, c1 = ((s1 & 3) - (r1 >> 1)) & 3;
        f32x4 acc[4][4];
        #pragma unroll
        for (int i = 0; i < 4; ++i)
            #pragma unroll
            for (int j = 0; j < 4; ++j) acc[i][j] = (f32x4){0.f, 0.f, 0.f, 0.f};
        for (int k0 = 0; k0 < NB2; k0 += 32) {
            __syncthreads();
            {
                const float* p0 = Af + (size_t)(m0 + r0) * NB2 + k0 + c0 * 8;
                const float* p1 = Af + (size_t)(m0 + r1) * NB2 + k0 + c1 * 8;
                *(uint4*)&sm.w.A[s0 * 8] = pack8(((const float4*)p0)[0], ((const float4*)p0)[1], 1.f);
                *(uint4*)&sm.w.A[s1 * 8] = pack8(((const float4*)p1)[0], ((const float4*)p1)[1], 1.f);
                const float* q0 = Bf + (size_t)(n0 + r0) * NB2 + k0 + c0 * 8;
                const float* q1 = Bf + (size_t)(n0 + r1) * NB2 + k0 + c1 * 8;
                *(uint4*)&sm.w.B[s0 * 8] = pack8(((const float4*)q0)[0], ((const float4*)q0)[1], scB);
                *(uint4*)&sm.w.B[s1 * 8] = pack8(((const float4*)q1)[0], ((const float4*)q1)[1], scB);
            }
            __syncthreads();
            bf16x8 af[4], bfr[4];
            #pragma unroll
            for (int mt = 0; mt < 4; ++mt) {
                const int r = wm + mt * 16 + l16;
                af[mt] = *(const bf16x8*)&sm.w.A[(r * 4 + ((qq + (r >> 1)) & 3)) * 8];
            }
            #pragma unroll
            for (int nt = 0; nt < 4; ++nt) {
                const int r = wn + nt * 16 + l16;
                bfr[nt] = *(const bf16x8*)&sm.w.B[(r * 4 + ((qq + (r >> 1)) & 3)) * 8];
            }
            #pragma unroll
            for (int mt = 0; mt < 4; ++mt)
                #pragma unroll
                for (int nt = 0; nt < 4; ++nt)
                    acc[mt][nt] = __builtin_amdgcn_mfma_f32_16x16x32_bf16(
                        af[mt], bfr[nt], acc[mt][nt], 0, 0, 0);
        }
        #pragma unroll
        for (int mt = 0; mt < 4; ++mt)
            #pragma unroll
            for (int rr = 0; rr < 4; ++rr) {
                int grow = m0 + wm + mt * 16 + qq * 4 + rr;
                #pragma unroll
                for (int nt = 0; nt < 4; ++nt)
                    Cp[(size_t)grow * 512 + n0 + wn + nt * 16 + l16] = f2bu(acc[mt][nt][rr]);
            }
    }
}

// ---------------------------------------------------------------------------
// q/k/v projection, 768 blocks, BK=32 dbuf, XCD-clustered, fp32-A staging
// with prefetch distance 2. [r10 champion, 148.97 us]
// ---------------------------------------------------------------------------
__global__ __launch_bounds__(256) void gemm_qkv3(
    const float* __restrict__ x, const u16* __restrict__ wcat,
    u16* __restrict__ qo, u16* __restrict__ ko, u16* __restrict__ vo,
    float* __restrict__ norms)
{
    __shared__ __align__(16) u16 As[8192];   // 2 x 4096 (dbuf)
    __shared__ __align__(16) u16 Bs[8192];
    const int t = threadIdx.x;
    const int wave = t >> 6, lane = t & 63;
    const int qq = lane >> 4, l16 = lane & 15;
    const int bid = blockIdx.x;
    const int fid = (bid & 7) * 96 + (bid >> 3);   // XCD-cluster swizzle (768%8==0)
    const int mx = fid % 12;
    const int sec = mx >> 2;
    const int n0 = (mx & 3) * 128;
    const int m0 = (fid / 12) * 128;
    const int wm = (wave >> 1) * 64, wn = (wave & 1) * 64;
    const int K = VV;
    const u16* Bt = wcat + (size_t)sec * VV * CC;

    const int s0 = wave * 128 + lane, s1 = s0 + 64;
    const int r0_ = s0 >> 2, c0_ = ((s0 & 3) - (r0_ >> 1)) & 3;
    const int r1_ = s1 >> 2, c1_ = ((s1 & 3) - (r1_ >> 1)) & 3;
    const float* gax0 = x + (size_t)(m0 + r0_) * K + c0_ * 8;
    const float* gax1 = x + (size_t)(m0 + r1_) * K + c1_ * 8;
    const u16* gb0 = Bt + (size_t)(n0 + r0_) * K + c0_ * 8;
    const u16* gb1 = Bt + (size_t)(n0 + r1_) * K + c1_ * 8;
    const int lo0 = (wave * 128) * 8, lo1 = lo0 + 512;   // gl_lds wave bases (B only)

    {
        float4 a0 = ((const float4*)gax0)[0], a1 = ((const float4*)gax0)[1];
        float4 b0 = ((const float4*)gax1)[0], b1 = ((const float4*)gax1)[1];
        *(uint4*)&As[s0 * 8] = pack8(a0, a1, 1.f);
        *(uint4*)&As[s1 * 8] = pack8(b0, b1, 1.f);
    }
    gl_lds16(gb0, Bs + lo0);
    gl_lds16(gb1, Bs + lo1);
    float4 na0 = ((const float4*)(gax0 + 32))[0];
    float4 na1 = ((const float4*)(gax0 + 32))[1];
    float4 nb0 = ((const float4*)(gax1 + 32))[0];
    float4 nb1 = ((const float4*)(gax1 + 32))[1];

    f32x4 acc[4][4];
    #pragma unroll
    for (int i = 0; i < 4; ++i)
        #pragma unroll
        for (int j = 0; j < 4; ++j) acc[i][j] = (f32x4){0.f, 0.f, 0.f, 0.f};

    int ib = 0;
    for (int k0 = 0; k0 < K; k0 += 32, ib ^= 1) {
        __syncthreads();                 // buf ib ready
        if (k0 + 32 < K) {
            *(uint4*)&As[(ib ^ 1) * 4096 + s0 * 8] = pack8(na0, na1, 1.f);
            *(uint4*)&As[(ib ^ 1) * 4096 + s1 * 8] = pack8(nb0, nb1, 1.f);
            gl_lds16(gb0 + k0 + 32, Bs + (ib ^ 1) * 4096 + lo0);
            gl_lds16(gb1 + k0 + 32, Bs + (ib ^ 1) * 4096 + lo1);
        }
        if (k0 + 64 < K) {
            na0 = ((const float4*)(gax0 + k0 + 64))[0];
            na1 = ((const float4*)(gax0 + k0 + 64))[1];
            nb0 = ((const float4*)(gax1 + k0 + 64))[0];
            nb1 = ((const float4*)(gax1 + k0 + 64))[1];
        }
        const u16* Ac = As + ib * 4096;
        const u16* Bc = Bs + ib * 4096;
        bf16x8 af[4], bfr[4];
        #pragma unroll
        for (int mt = 0; mt < 4; ++mt) {
            const int r = wm + mt * 16 + l16;
            af[mt] = *(const bf16x8*)&Ac[(r * 4 + ((qq + (r >> 1)) & 3)) * 8];
        }
        #pragma unroll
        for (int nt = 0; nt < 4; ++nt) {
            const int r = wn + nt * 16 + l16;
            bfr[nt] = *(const bf16x8*)&Bc[(r * 4 + ((qq + (r >> 1)) & 3)) * 8];
        }
        #pragma unroll
        for (int mt = 0; mt < 4; ++mt)
            #pragma unroll
            for (int nt = 0; nt < 4; ++nt)
                acc[mt][nt] = __builtin_amdgcn_mfma_f32_16x16x32_bf16(
                    af[mt], bfr[nt], acc[mt][nt], 0, 0, 0);
    }

    u16* outp = sec == 0 ? qo : (sec == 1 ? ko : vo);
    #pragma unroll
    for (int mt = 0; mt < 4; ++mt)
        #pragma unroll
        for (int r = 0; r < 4; ++r) {
            int grow = m0 + wm + mt * 16 + qq * 4 + r;
            #pragma unroll
            for (int nt = 0; nt < 4; ++nt)
                outp[(size_t)grow * CC + n0 + wn + nt * 16 + l16] =
                    f2bu(acc[mt][nt][r]);
        }
    if (sec < 2) {
        float* np = sec == 0 ? norms : norms + NROWS;
        #pragma unroll
        for (int mt = 0; mt < 4; ++mt)
            #pragma unroll
            for (int r = 0; r < 4; ++r) {
                float s = 0.f;
                #pragma unroll
                for (int nt = 0; nt < 4; ++nt) {
                    float v = acc[mt][nt][r];
                    s = fmaf(v, v, s);
                }
                s += __shfl_xor(s, 1, 64);
                s += __shfl_xor(s, 2, 64);
                s += __shfl_xor(s, 4, 64);
                s += __shfl_xor(s, 8, 64);
                if (l16 == 0)
                    atomicAdd(&np[m0 + wm + mt * 16 + qq * 4 + r], s);
            }
    }
}

// ---------------------------------------------------------------------------
// per-chunk local states via MFMA [r10 version]
// ---------------------------------------------------------------------------
__global__ __launch_bounds__(256) void state_local(
    const u16* __restrict__ kb, const u16* __restrict__ vb,
    const float* __restrict__ norms_k, const float* __restrict__ dlog,
    u16* __restrict__ statesb)
{
    __shared__ __align__(16) u16 vT[DD][SST];
    __shared__ __align__(16) u16 kT[DD][SST];
    const int c = blockIdx.x, bh = blockIdx.y;
    const int b = bh >> 2, h = bh & 3;
    const float lam = 1.f / (1.f + __expf(-dlog[h]));
    const float l2lam = log2f(lam);
    const int t = threadIdx.x;
    const int row0 = b * TT + c * QC;
    const size_t gbase = (size_t)row0 * CC + h * DD;

    {
        const int j2 = t & 31, d0 = (t >> 5) * 16;
        const int jj0 = 2 * j2, jj1 = jj0 + 1;
        const float w0 = exp2f((float)jj0 * l2lam);
        const float w1 = exp2f((float)jj1 * l2lam);
        const float rk0 = 1.f / fmaxf(sqrtf(norms_k[row0 + jj0]), EPS);
        const float rk1 = 1.f / fmaxf(sqrtf(norms_k[row0 + jj1]), EPS);
        u16 k0a[16], k1a[16], v0a[16], v1a[16];
        const u16* k0p = kb + gbase + (size_t)jj0 * CC + d0;
        const u16* k1p = kb + gbase + (size_t)jj1 * CC + d0;
        const u16* v0p = vb + gbase + (size_t)jj0 * CC + d0;
        const u16* v1p = vb + gbase + (size_t)jj1 * CC + d0;
        *(uint4*)&k0a[0] = *(const uint4*)k0p; *(uint4*)&k0a[8] = *(const uint4*)(k0p + 8);
        *(uint4*)&k1a[0] = *(const uint4*)k1p; *(uint4*)&k1a[8] = *(const uint4*)(k1p + 8);
        *(uint4*)&v0a[0] = *(const uint4*)v0p; *(uint4*)&v0a[8] = *(const uint4*)(v0p + 8);
        *(uint4*)&v1a[0] = *(const uint4*)v1p; *(uint4*)&v1a[8] = *(const uint4*)(v1p + 8);
        #pragma unroll
        for (int i = 0; i < 16; ++i) {
            unsigned int kw = (unsigned int)f2bu(bu2f(k0a[i]) * rk0)
                            | ((unsigned int)f2bu(bu2f(k1a[i]) * rk1) << 16);
            *(unsigned int*)&kT[d0 + i][jj0] = kw;
            unsigned int vw = (unsigned int)f2bu(bu2f(v0a[i]) * w0)
                            | ((unsigned int)f2bu(bu2f(v1a[i]) * w1) << 16);
            *(unsigned int*)&vT[d0 + i][jj0] = vw;
        }
    }
    __syncthreads();

    const int wave = t >> 6, lane = t & 63;
    const int quad = lane >> 4, l16 = lane & 15;
    f32x4 acc[2][8];
    #pragma unroll
    for (int i = 0; i < 2; ++i)
        #pragma unroll
        for (int j = 0; j < 8; ++j) acc[i][j] = (f32x4){0.f, 0.f, 0.f, 0.f};

    #pragma unroll
    for (int s = 0; s < 2; ++s) {
        bf16x8 af[2];
        #pragma unroll
        for (int mt = 0; mt < 2; ++mt)
            af[mt] = *(const bf16x8*)&vT[wave * 32 + mt * 16 + l16][s * 32 + quad * 8];
        #pragma unroll
        for (int nt = 0; nt < 8; ++nt) {
            bf16x8 bk = *(const bf16x8*)&kT[nt * 16 + l16][s * 32 + quad * 8];
            #pragma unroll
            for (int mt = 0; mt < 2; ++mt)
                acc[mt][nt] = __builtin_amdgcn_mfma_f32_16x16x32_bf16(
                    af[mt], bk, acc[mt][nt], 0, 0, 0);
        }
    }
    u16* so = statesb + ((size_t)(bh * NCH + c) << 14);
    #pragma unroll
    for (int mt = 0; mt < 2; ++mt)
        #pragma unroll
        for (int rr = 0; rr < 4; ++rr) {
            const int d = wave * 32 + mt * 16 + quad * 4 + rr;
            #pragma unroll
            for (int nt = 0; nt < 8; ++nt)
                so[(size_t)d * DD + nt * 16 + l16] = f2bu(acc[mt][nt][rr]);
        }
}

// ---------------------------------------------------------------------------
// suffix combine: all 32 chunk values preloaded to registers. [validated]
// ---------------------------------------------------------------------------
__global__ __launch_bounds__(256) void state_combine512(
    const float* __restrict__ dlog, u16* __restrict__ statesb)
{
    const int bh = blockIdx.x >> 5, part = blockIdx.x & 31;
    const int h = bh & 3;
    const float lam = 1.f / (1.f + __expf(-dlog[h]));
    const float lamQ = exp2f((float)QC * log2f(lam));
    const int t = threadIdx.x;
    unsigned int* pb = (unsigned int*)(statesb + ((size_t)(bh * NCH) << 14))
                       + part * 256 + t;
    unsigned int vals[NCH];
    #pragma unroll
    for (int c = 0; c < NCH; ++c) vals[c] = pb[(size_t)c * 8192];
    float run0 = 0.f, run1 = 0.f;
    #pragma unroll
    for (int c = NCH - 1; c >= 0; --c) {
        float t0 = bu2f((u16)(vals[c] & 0xffffu));
        float t1 = bu2f((u16)(vals[c] >> 16));
        pb[(size_t)c * 8192] = (unsigned int)f2bu(run0)
                             | ((unsigned int)f2bu(run1) << 16);
        run0 = fmaf(lamQ, run0, t0);
        run1 = fmaf(lamQ, run1, t1);
    }
}

// ---------------------------------------------------------------------------
// fused MFMA attention. [r10 version]
// ---------------------------------------------------------------------------
__global__ __launch_bounds__(256) void attention_fused(
    const u16* __restrict__ qb, const u16* __restrict__ kb,
    const u16* __restrict__ vb, const u16* __restrict__ statesb,
    const float* __restrict__ norms, const float* __restrict__ dlog,
    u16* __restrict__ retb)
{
    __shared__ __align__(16) u16 qks[2 * QC * DD];
    __shared__ __align__(16) u16 vsT[DD][SST];
    __shared__ __align__(16) u16 ss[QC][SST];
    __shared__ float rql[QC], rkl[QC];

    const int c = blockIdx.x, bh = blockIdx.y;
    const int b = bh >> 2, h = bh & 3;
    const float lam = 1.f / (1.f + __expf(-dlog[h]));
    const float l2lam = log2f(lam);
    const int t = threadIdx.x;
    const int row0 = b * TT + c * QC;
    const size_t base = (size_t)row0 * CC + h * DD;

    const int wave = t >> 6, lane = t & 63;
    const int quad = lane >> 4, l16 = lane & 15;
    const int r0 = wave * 16;

    {
        const int lrow = lane >> 4, cch = lane & 15;
        #pragma unroll
        for (int u = 0; u < 4; ++u) {
            const int R = wave * 16 + u * 4;
            const int gr = R + lrow;
            const int cq = (cch - gr) & 15;
            gl_lds16(qb + base + (size_t)gr * CC + cq * 8, &qks[R * DD]);
            gl_lds16(kb + base + (size_t)gr * CC + cq * 8, &qks[(QC + R) * DD]);
        }
    }
    if (t < QC)            rql[t]      = 1.f / fmaxf(sqrtf(norms[row0 + t]), EPS);
    else if (t < 2 * QC)   rkl[t - QC] = 1.f / fmaxf(sqrtf(norms[NROWS + row0 + t - QC]), EPS);
    {
        const int j2 = t & 31, d0 = (t >> 5) * 16;
        const u16* v0 = vb + base + (size_t)(2 * j2) * CC + d0;
        const u16* v1 = v0 + CC;
        uint4 a0 = *(const uint4*)v0;
        uint4 a1 = *(const uint4*)(v0 + 8);
        uint4 b0 = *(const uint4*)v1;
        uint4 b1 = *(const uint4*)(v1 + 8);
        const u16* ap0 = (const u16*)&a0; const u16* ap1 = (const u16*)&a1;
        const u16* bp0 = (const u16*)&b0; const u16* bp1 = (const u16*)&b1;
        #pragma unroll
        for (int i = 0; i < 8; ++i) {
            *(unsigned int*)&vsT[d0 + i][2 * j2] =
                (unsigned int)ap0[i] | ((unsigned int)bp0[i] << 16);
            *(unsigned int*)&vsT[d0 + 8 + i][2 * j2] =
                (unsigned int)ap1[i] | ((unsigned int)bp1[i] << 16);
        }
    }
    __syncthreads();

    bf16x8 aq[4];
    #pragma unroll
    for (int kq = 0; kq < 4; ++kq) {
        const int r = r0 + l16;
        aq[kq] = *(const bf16x8*)&qks[r * DD + ((kq * 4 + quad + r) & 15) * 8];
    }

    f32x4 accs[4];
    #pragma unroll
    for (int nt = 0; nt < 4; ++nt) accs[nt] = (f32x4){0.f, 0.f, 0.f, 0.f};
    #pragma unroll
    for (int nt = 0; nt < 4; ++nt)
        #pragma unroll
        for (int kq = 0; kq < 4; ++kq) {
            const int rk_ = nt * 16 + l16;
            bf16x8 bk = *(const bf16x8*)&qks[(QC + rk_) * DD + ((kq * 4 + quad + rk_) & 15) * 8];
            accs[nt] = __builtin_amdgcn_mfma_f32_16x16x32_bf16(aq[kq], bk, accs[nt], 0, 0, 0);
        }

    #pragma unroll
    for (int nt = 0; nt < 4; ++nt) {
        const int j = nt * 16 + l16;
        const float rkj = rkl[j];
        #pragma unroll
        for (int rr = 0; rr < 4; ++rr) {
            const int i = r0 + quad * 4 + rr;
            const int di = j - i;
            float p = (di > 0) ? accs[nt][rr] * exp2f((float)(di - 1) * l2lam) * rkj : 0.f;
            ss[i][j] = f2bu(p);
        }
    }
    __syncthreads();

    const u16* sb = statesb + ((size_t)(bh * NCH + c) << 14);
    {
        const int drow = lane >> 4, cch = lane & 15;
        #pragma unroll
        for (int u = 0; u < 8; ++u) {
            const int D = wave * 32 + u * 4;
            const int gd = D + drow;
            const int cq = (cch - gd) & 15;
            gl_lds16(sb + (size_t)gd * DD + cq * 8, &qks[D * DD]);
        }
    }
    bf16x8 ap[2];
    #pragma unroll
    for (int kj = 0; kj < 2; ++kj)
        ap[kj] = *(const bf16x8*)&ss[r0 + l16][kj * 32 + quad * 8];
    f32x4 accd[8];
    #pragma unroll
    for (int nt = 0; nt < 8; ++nt) accd[nt] = (f32x4){0.f, 0.f, 0.f, 0.f};
    #pragma unroll
    for (int nt = 0; nt < 8; ++nt)
        #pragma unroll
        for (int kj = 0; kj < 2; ++kj) {
            bf16x8 bv = *(const bf16x8*)&vsT[nt * 16 + l16][kj * 32 + quad * 8];
            accd[nt] = __builtin_amdgcn_mfma_f32_16x16x32_bf16(ap[kj], bv, accd[nt], 0, 0, 0);
        }
    __syncthreads();

    f32x4 accc[8];
    #pragma unroll
    for (int nt = 0; nt < 8; ++nt) accc[nt] = (f32x4){0.f, 0.f, 0.f, 0.f};
    #pragma unroll
    for (int nt = 0; nt < 8; ++nt)
        #pragma unroll
        for (int kq = 0; kq < 4; ++kq) {
            const int d = nt * 16 + l16;
            bf16x8 bs_ = *(const bf16x8*)&qks[d * DD + ((kq * 4 + quad + d) & 15) * 8];
            accc[nt] = __builtin_amdgcn_mfma_f32_16x16x32_bf16(aq[kq], bs_, accc[nt], 0, 0, 0);
        }

    u16* rb = retb + (size_t)row0 * CC + h * DD;
    #pragma unroll
    for (int rr = 0; rr < 4; ++rr) {
        const int ii = r0 + quad * 4 + rr;
        const float wrow = exp2f((float)(QC - 1 - ii) * l2lam);
        const float rq = rql[ii];
        #pragma unroll
        for (int nt = 0; nt < 8; ++nt) {
            float val = (accd[nt][rr] + wrow * accc[nt][rr]) * rq;
            rb[(size_t)ii * CC + nt * 16 + l16] = f2bu(val);
        }
    }
}

// ---------------------------------------------------------------------------
// output projection, 64x128 tile, XCD-clustered [validated r10]
// ---------------------------------------------------------------------------
__global__ __launch_bounds__(256) void gemm_out64(
    const u16* __restrict__ A, const u16* __restrict__ Bt, float* __restrict__ C)
{
    __shared__ __align__(16) u16 As[4096];
    __shared__ __align__(16) u16 Bs[8192];
    const int t = threadIdx.x;
    const int wave = t >> 6, lane = t & 63;
    const int qq = lane >> 4, l16 = lane & 15;
    const int bid = blockIdx.x;
    const int fid = (bid & 7) * 64 + (bid >> 3);   // XCD-cluster (512%8==0)
    const int m0 = (fid >> 2) * 64, n0 = (fid & 3) * 128;
    const int wm = (wave >> 1) * 32, wn = (wave & 1) * 64;
    const int N = VV, K = CC;

    const int sA = wave * 64 + lane;
    const int rA = sA >> 2, cA = ((sA & 3) - (rA >> 1)) & 3;
    const int sB0 = wave * 128 + lane, sB1 = sB0 + 64;
    const int rB0 = sB0 >> 2, cB0 = ((sB0 & 3) - (rB0 >> 1)) & 3;
    const int rB1 = sB1 >> 2, cB1 = ((sB1 & 3) - (rB1 >> 1)) & 3;
    const u16* ga  = A  + (size_t)(m0 + rA) * K + cA * 8;
    const u16* gb0 = Bt + (size_t)(n0 + rB0) * K + cB0 * 8;
    const u16* gb1 = Bt + (size_t)(n0 + rB1) * K + cB1 * 8;
    const int loA = wave * 512, loB0 = wave * 1024, loB1 = wave * 1024 + 512;

    gl_lds16(ga, As + loA);
    gl_lds16(gb0, Bs + loB0);
    gl_lds16(gb1, Bs + loB1);

    f32x4 acc[2][4];
    #pragma unroll
    for (int i = 0; i < 2; ++i)
        #pragma unroll
        for (int j = 0; j < 4; ++j) acc[i][j] = (f32x4){0.f, 0.f, 0.f, 0.f};

    int ib = 0;
    for (int k0 = 0; k0 < K; k0 += 32, ib ^= 1) {
        __syncthreads();
        if (k0 + 32 < K) {
            gl_lds16(ga + k0 + 32,  As + (ib ^ 1) * 2048 + loA);
            gl_lds16(gb0 + k0 + 32, Bs + (ib ^ 1) * 4096 + loB0);
            gl_lds16(gb1 + k0 + 32, Bs + (ib ^ 1) * 4096 + loB1);
        }
        const u16* Ac = As + ib * 2048;
        const u16* Bc = Bs + ib * 4096;
        bf16x8 af[2], bfr[4];
        #pragma unroll
        for (int mt = 0; mt < 2; ++mt) {
            const int r = wm + mt * 16 + l16;
            af[mt] = *(const bf16x8*)&Ac[(r * 4 + ((qq + (r >> 1)) & 3)) * 8];
        }
        #pragma unroll
        for (int nt = 0; nt < 4; ++nt) {
            const int r = wn + nt * 16 + l16;
            bfr[nt] = *(const bf16x8*)&Bc[(r * 4 + ((qq + (r >> 1)) & 3)) * 8];
        }
        #pragma unroll
        for (int mt = 0; mt < 2; ++mt)
            #pragma unroll
            for (int nt = 0; nt < 4; ++nt)
                acc[mt][nt] = __builtin_amdgcn_mfma_f32_16x16x32_bf16(
                    af[mt], bfr[nt], acc[mt][nt], 0, 0, 0);
    }
    #pragma unroll
    for (int mt = 0; mt < 2; ++mt)
        #pragma unroll
        for (int r = 0; r < 4; ++r) {
            int grow = m0 + wm + mt * 16 + qq * 4 + r;
            #pragma unroll
            for (int nt = 0; nt < 4; ++nt)
                C[(size_t)grow * N + n0 + wn + nt * 16 + l16] = acc[mt][nt][r];
        }
}

// ---------------------------------------------------------------------------
extern "C" void kernel_launch(void* const* d_in, const int* in_sizes, int n_in,
                              void* d_out, int out_size, void* d_ws, size_t ws_size,
                              hipStream_t stream) {
    const float* x         = (const float*)d_in[0];
    const float* basis     = (const float*)d_in[1];
    const float* qw        = (const float*)d_in[2];
    const float* kw        = (const float*)d_in[3];
    const float* v_coeffs  = (const float*)d_in[4];
    const float* o_coeffs  = (const float*)d_in[5];
    const float* dlog      = (const float*)d_in[6];
    const float* out_scale = (const float*)d_in[7];
    float* out             = (float*)d_out;

    u16* p = (u16*)d_ws;
    u16* qb      = p;                                   // 8192*512 bf16
    u16* kb      = qb + (size_t)NROWS * CC;
    u16* vb      = kb + (size_t)NROWS * CC;
    u16* statesb = vb + (size_t)NROWS * CC;             // 16*32*16384 bf16
    u16* retb    = statesb + (size_t)BB * HH * NCH * DD * DD;
    u16* wcat    = retb + (size_t)NROWS * CC;           // 3 x 512x512 bf16
    u16* o_ws    = wcat + 3 * (size_t)VV * CC;
    float* norms = (float*)(o_ws + (size_t)VV * CC);    // 2 x 8192 fp32 (q, k)

    // 1. transposes / zero norms / small weight GEMMs
    prep_all4<<<P4_TR + P4_Z + P4_WG, 256, 0, stream>>>(
        qw, kw, basis, v_coeffs, o_coeffs, out_scale,
        wcat, wcat + (size_t)VV * CC, wcat + 2 * (size_t)VV * CC, o_ws, norms);
    // 2. q/k/v projection (fp32-A staging, prefetch 2, XCD-clustered)
    gemm_qkv3<<<768, 256, 0, stream>>>(x, wcat, qb, kb, vb, norms);
    // 3. chunked linear attention
    state_local     <<<dim3(NCH, BB * HH), 256, 0, stream>>>(kb, vb, norms + NROWS,
                                                             dlog, statesb);
    state_combine512<<<BB * HH * 32, 256, 0, stream>>>(dlog, statesb);
    attention_fused <<<dim3(NCH, BB * HH), 256, 0, stream>>>(qb, kb, vb, statesb,
                                                             norms, dlog, retb);
    // 4. output projection (o_ws includes out_scale), fp32 out (XCD-clustered)
    gemm_out64<<<512, 256, 0, stream>>>(retb, o_ws, out);
}